// Round 1
// baseline (367.029 us; speedup 1.0000x reference)
//
#include <hip/hip_runtime.h>
#include <math.h>

namespace {
constexpr int kB = 8, kC = 64, kD = 32, kH = 64, kW = 64;
constexpr int kHW      = kH * kW;        // 4096
constexpr int kDHW     = kD * kHW;       // 131072
constexpr int kSpatial = kB * kDHW;      // 1048576
constexpr int kCs4     = kDHW / 4;       // channel stride in float4 units
}

// Kernel 1: per-spatial-position mean and max over the 64 channels.
// One thread = 4 consecutive w positions (float4). Lane i of a wave reads
// 16 contiguous bytes; the wave reads 1 KiB contiguous per channel step.
__global__ __launch_bounds__(256) void reduce_mean_max(
        const float* __restrict__ x,
        float* __restrict__ avg,
        float* __restrict__ mx) {
    int tid = blockIdx.x * blockDim.x + threadIdx.x;   // [0, kSpatial/4)
    int s   = tid * 4;                                  // flat spatial index
    int b   = s / kDHW;
    int rem = s - b * kDHW;
    const float4* xp = (const float4*)(x + (size_t)b * (size_t)kC * kDHW + rem);

    float4 sum = make_float4(0.f, 0.f, 0.f, 0.f);
    float4 m   = make_float4(-INFINITY, -INFINITY, -INFINITY, -INFINITY);
    #pragma unroll 8
    for (int c = 0; c < kC; ++c) {
        float4 t = xp[(size_t)c * kCs4];
        sum.x += t.x; sum.y += t.y; sum.z += t.z; sum.w += t.w;
        m.x = fmaxf(m.x, t.x); m.y = fmaxf(m.y, t.y);
        m.z = fmaxf(m.z, t.z); m.w = fmaxf(m.w, t.w);
    }
    const float inv = 1.0f / (float)kC;
    float4 a = make_float4(sum.x * inv, sum.y * inv, sum.z * inv, sum.w * inv);
    ((float4*)avg)[tid] = a;
    ((float4*)mx)[tid]  = m;
}

// Kernel 2: 3x3x3 cross-correlation over [avg, max] channels, SAME zero pad,
// fused sigmoid. Weights layout W[0][i][kd][kh][kw]: i=0 -> avg, i=1 -> max.
__global__ __launch_bounds__(256) void conv_sigmoid(
        const float* __restrict__ avg,
        const float* __restrict__ mx,
        const float* __restrict__ wts,
        float* __restrict__ out) {
    __shared__ float w[54];
    if (threadIdx.x < 54) w[threadIdx.x] = wts[threadIdx.x];
    __syncthreads();

    int tid = blockIdx.x * blockDim.x + threadIdx.x;   // [0, kSpatial)
    int wp = tid & (kW - 1);
    int h  = (tid >> 6) & (kH - 1);
    int bd = tid / kHW;              // b*kD + d  (b-major layout)
    int d  = bd & (kD - 1);
    int b  = bd >> 5;

    float acc = 0.f;
    #pragma unroll
    for (int kd = 0; kd < 3; ++kd) {
        int dd = d + kd - 1;
        if (dd < 0 || dd >= kD) continue;
        #pragma unroll
        for (int kh = 0; kh < 3; ++kh) {
            int hh = h + kh - 1;
            if (hh < 0 || hh >= kH) continue;
            size_t rowbase = (size_t)b * kDHW + (size_t)dd * kHW + (size_t)hh * kW;
            #pragma unroll
            for (int kw = 0; kw < 3; ++kw) {
                int ww = wp + kw - 1;
                if (ww < 0 || ww >= kW) continue;
                int widx = (kd * 3 + kh) * 3 + kw;
                size_t idx = rowbase + (size_t)ww;
                acc = fmaf(avg[idx], w[widx],      acc);
                acc = fmaf(mx[idx],  w[27 + widx], acc);
            }
        }
    }
    out[tid] = 1.0f / (1.0f + expf(-acc));
}

extern "C" void kernel_launch(void* const* d_in, const int* in_sizes, int n_in,
                              void* d_out, int out_size, void* d_ws, size_t ws_size,
                              hipStream_t stream) {
    const float* x   = (const float*)d_in[0];
    const float* wts = (const float*)d_in[1];
    float* out = (float*)d_out;

    float* avg = (float*)d_ws;            // kSpatial floats (4 MiB)
    float* mx  = avg + kSpatial;          // kSpatial floats (4 MiB)

    {
        int threads = 256;
        int blocks  = (kSpatial / 4) / threads;   // 1024
        reduce_mean_max<<<blocks, threads, 0, stream>>>(x, avg, mx);
    }
    {
        int threads = 256;
        int blocks  = kSpatial / threads;         // 4096
        conv_sigmoid<<<blocks, threads, 0, stream>>>(avg, mx, wts, out);
    }
}